// Round 2
// baseline (1120.963 us; speedup 1.0000x reference)
//
#include <hip/hip_runtime.h>
#include <math.h>

// VectorQuantizer on MI355X.
// latents [64,256,32,32] f32, embedding [1024,256] f32.
// Outputs (concat fp32): quant_st [16777216], loss [1], indices-as-float [65536].
//
// Index semantics target: numpy float32 reference
//   dist = fl32( fl32(Sx + Ek) - fl32(2*dot) ), argmin first-index ties,
// where Sx/Ek use numpy pairwise summation (8-accumulator blocks of 128) and
// dot is a sequential ascending-k fp32 FMA chain (BLAS GEBP microkernel order).
//
// Pipeline:
//  k_prep  : Ek[k] = numpy-pairwise fp32 sum(e_k^2); zero loss/count
//  k_score : tiled fp32 GEMM top-2 filter; gap >= MARGIN_Q -> emit index;
//            else append pixel to worklist
//  k_refine: per flagged pixel, full 1024-code re-scan with exact np semantics
//  k_gather: gather + straight-through write + fp64 loss partials
//  k_loss  : loss = 1.25 * total / 16777216

#define DIM 256
#define BSTRIDE 262144      // 256*1024 elements per batch image
#define OUT_LOSS 16777216
#define OUT_IDX  16777217
#define MARGIN_Q 3e-4f      // quantization wobble bound ~6.5e-5; 4.5x safety

// ws byte offsets (~532 KB)
#define WS_LOSS  0
#define WS_COUNT 8
#define WS_ENORM 64
#define WS_SEL   8192
#define WS_WL    (8192 + 262144)

// ---------------- k_prep: numpy-pairwise |e_k|^2, zero accumulators ---------
__global__ void k_prep(const float* __restrict__ emb, float* __restrict__ enormQ,
                       double* __restrict__ lossAcc, int* __restrict__ count) {
  const int k = blockIdx.x * 64 + threadIdx.x;   // 16 blocks x 64
  if (blockIdx.x == 0 && threadIdx.x == 0) { *lossAcc = 0.0; *count = 0; }
  if (k >= 1024) return;
  const float* e = emb + (size_t)k * DIM;
  float blk[2];
  #pragma unroll
  for (int h = 0; h < 2; ++h) {
    const float* a = e + h * 128;
    float r[8];
    #pragma unroll
    for (int j = 0; j < 8; ++j) r[j] = __fmul_rn(a[j], a[j]);
    for (int i = 8; i < 128; i += 8)
      #pragma unroll
      for (int j = 0; j < 8; ++j) r[j] = __fadd_rn(r[j], __fmul_rn(a[i+j], a[i+j]));
    blk[h] = __fadd_rn(__fadd_rn(__fadd_rn(r[0], r[1]), __fadd_rn(r[2], r[3])),
                       __fadd_rn(__fadd_rn(r[4], r[5]), __fadd_rn(r[6], r[7])));
  }
  enormQ[k] = __fadd_rn(blk[0], blk[1]);
}

// ---------------- k_score: fp32 tiled scoring + top-2 filter ----------------
// 1024 blocks x 256 threads; block = 64 pixels. Thread micro-tile 8x8.
__launch_bounds__(256, 2)
__global__ void k_score(const float* __restrict__ lat, const float* __restrict__ emb,
                        const float* __restrict__ enormQ,
                        int* __restrict__ selIdx, float* __restrict__ out,
                        int* __restrict__ count, int* __restrict__ worklist) {
  __shared__ __align__(16) float smem[128*64 + 16*256];  // 48 KB
  float* latA = smem;            // [128][64]
  float* embB = smem + 128*64;   // [16][256]

  const int t = threadIdx.x;
  const int pix0 = blockIdx.x * 64;
  const int b = pix0 >> 10;
  const int hw0 = pix0 & 1023;
  const float* latBase = lat + (size_t)b * BSTRIDE + hw0;

  const int tm = t & 7;
  const int tn = t >> 3;

  float b1v[8], b2v[8];
  int i1v[8], i2v[8];
  #pragma unroll
  for (int p = 0; p < 8; ++p) { b1v[p] = INFINITY; b2v[p] = INFINITY; i1v[p] = 0; i2v[p] = 0; }

  const int cSub = t >> 4;
  const int p4   = (t & 15) * 4;
  const int eq   = t & 3;
  const int erb  = (t >> 2) * 4;

  for (int chunk = 0; chunk < 4; ++chunk) {
    const int kBase = chunk * 256;
    float acc[8][8];
    #pragma unroll
    for (int p = 0; p < 8; ++p)
      #pragma unroll
      for (int j = 0; j < 8; ++j) acc[p][j] = 0.0f;

    for (int half = 0; half < 2; ++half) {
      const int cHalf = half * 128;
      __syncthreads();
      #pragma unroll
      for (int i = 0; i < 8; ++i) {
        int c = i * 16 + cSub;
        float4 v = *(const float4*)(latBase + (size_t)(cHalf + c) * 1024 + p4);
        *(float4*)(latA + c * 64 + p4) = v;
      }
      for (int stageI = 0; stageI < 8; ++stageI) {
        const int c0 = stageI * 16;
        __syncthreads();
        #pragma unroll
        for (int i = 0; i < 4; ++i) {
          int n = erb + i;
          float4 v = *(const float4*)(emb + (size_t)(kBase + n) * DIM + cHalf + c0 + eq * 4);
          embB[(eq*4 + 0) * 256 + n] = v.x;
          embB[(eq*4 + 1) * 256 + n] = v.y;
          embB[(eq*4 + 2) * 256 + n] = v.z;
          embB[(eq*4 + 3) * 256 + n] = v.w;
        }
        __syncthreads();
        #pragma unroll
        for (int kc = 0; kc < 16; ++kc) {
          float4 l0 = *(const float4*)(latA + (c0 + kc) * 64 + tm * 8);
          float4 l1 = *(const float4*)(latA + (c0 + kc) * 64 + tm * 8 + 4);
          float4 e0 = *(const float4*)(embB + kc * 256 + tn * 8);
          float4 e1 = *(const float4*)(embB + kc * 256 + tn * 8 + 4);
          float lv[8] = {l0.x,l0.y,l0.z,l0.w,l1.x,l1.y,l1.z,l1.w};
          float ev[8] = {e0.x,e0.y,e0.z,e0.w,e1.x,e1.y,e1.z,e1.w};
          #pragma unroll
          for (int p = 0; p < 8; ++p)
            #pragma unroll
            for (int j = 0; j < 8; ++j)
              acc[p][j] = fmaf(lv[p], ev[j], acc[p][j]);
        }
      }
    }
    #pragma unroll
    for (int j = 0; j < 8; ++j) {
      const int kIdx = kBase + tn * 8 + j;
      const float en = enormQ[kIdx];
      #pragma unroll
      for (int p = 0; p < 8; ++p) {
        float s = fmaf(-2.0f, acc[p][j], en);
        if (s < b1v[p])      { b2v[p] = b1v[p]; i2v[p] = i1v[p]; b1v[p] = s; i1v[p] = kIdx; }
        else if (s < b2v[p]) { b2v[p] = s; i2v[p] = kIdx; }
      }
    }
  }

  // merge top-2 across the 32 tn-threads per pixel
  __syncthreads();
  float4* mb = (float4*)smem;   // [64][33] float4
  #pragma unroll
  for (int p = 0; p < 8; ++p) {
    float4 v;
    v.x = b1v[p]; v.y = b2v[p];
    v.z = __int_as_float(i1v[p]); v.w = __int_as_float(i2v[p]);
    mb[(tm * 8 + p) * 33 + tn] = v;
  }
  __syncthreads();
  if (t < 64) {
    float B1 = INFINITY, B2 = INFINITY;
    int I1 = 0, I2 = 0;
    for (int j = 0; j < 32; ++j) {
      float4 v = mb[t * 33 + j];
      float c1 = v.x, c2 = v.y;
      int ci1 = __float_as_int(v.z), ci2 = __float_as_int(v.w);
      if (c1 < B1 || (c1 == B1 && ci1 < I1)) { B2 = B1; I2 = I1; B1 = c1; I1 = ci1; }
      else if (c1 < B2 || (c1 == B2 && ci1 < I2)) { B2 = c1; I2 = ci1; }
      if (c2 < B1 || (c2 == B1 && ci2 < I1)) { B2 = B1; I2 = I1; B1 = c2; I1 = ci2; }
      else if (c2 < B2 || (c2 == B2 && ci2 < I2)) { B2 = c2; I2 = ci2; }
    }
    const int pix = pix0 + t;
    if (B2 - B1 >= MARGIN_Q) {
      selIdx[pix] = I1;
      out[OUT_IDX + pix] = (float)I1;
    } else {
      int pos = atomicAdd(count, 1);
      worklist[pos] = pix;
    }
  }
}

// ---------------- k_refine: exact numpy-fp32 re-scan of flagged pixels ------
// 512 blocks x 256 threads = 2048 waves; one wave per flagged pixel.
__global__ void k_refine(const float* __restrict__ lat, const float* __restrict__ emb,
                         const float* __restrict__ enormQ,
                         const int* __restrict__ count, const int* __restrict__ worklist,
                         int* __restrict__ selIdx, float* __restrict__ out) {
  __shared__ float sx[4][256];
  const int lane = threadIdx.x & 63;
  const int wIn = threadIdx.x >> 6;
  const int wGlob = blockIdx.x * 4 + wIn;
  const int n = *count;
  float* sxw = sx[wIn];

  for (int wi = wGlob; wi < n; wi += 2048) {
    const int pix = worklist[wi];
    const int b = pix >> 10, hw = pix & 1023;
    const float* latB = lat + (size_t)b * BSTRIDE + hw;
    // stage x into this wave's LDS row (wave-lockstep: no block barrier needed)
    #pragma unroll
    for (int i = 0; i < 4; ++i)
      sxw[lane + i * 64] = latB[(size_t)(lane + i * 64) * 1024];

    // Sx = numpy pairwise fp32 of x^2 (all lanes redundantly; LDS broadcast)
    float blk[2];
    #pragma unroll
    for (int h = 0; h < 2; ++h) {
      const float* a = sxw + h * 128;
      float r[8];
      #pragma unroll
      for (int j = 0; j < 8; ++j) r[j] = __fmul_rn(a[j], a[j]);
      for (int i = 8; i < 128; i += 8)
        #pragma unroll
        for (int j = 0; j < 8; ++j) r[j] = __fadd_rn(r[j], __fmul_rn(a[i+j], a[i+j]));
      blk[h] = __fadd_rn(__fadd_rn(__fadd_rn(r[0], r[1]), __fadd_rn(r[2], r[3])),
                         __fadd_rn(__fadd_rn(r[4], r[5]), __fadd_rn(r[6], r[7])));
    }
    const float Sx = __fadd_rn(blk[0], blk[1]);

    // each lane scans 16 codes (k = lane*16 + j), 2 interleaved FMA chains
    float best = INFINITY;
    int bi = 0;
    for (int j = 0; j < 16; j += 2) {
      const int k0 = lane * 16 + j;
      const int k1 = k0 + 1;
      const float* e0 = emb + (size_t)k0 * DIM;
      const float* e1 = emb + (size_t)k1 * DIM;
      float d0 = 0.0f, d1 = 0.0f;
      for (int c = 0; c < 256; c += 4) {
        float4 a0 = *(const float4*)(e0 + c);
        float4 a1 = *(const float4*)(e1 + c);
        float x0 = sxw[c], x1 = sxw[c+1], x2 = sxw[c+2], x3 = sxw[c+3];
        d0 = fmaf(x0, a0.x, d0); d1 = fmaf(x0, a1.x, d1);
        d0 = fmaf(x1, a0.y, d0); d1 = fmaf(x1, a1.y, d1);
        d0 = fmaf(x2, a0.z, d0); d1 = fmaf(x2, a1.z, d1);
        d0 = fmaf(x3, a0.w, d0); d1 = fmaf(x3, a1.w, d1);
      }
      float dq0 = __fsub_rn(__fadd_rn(Sx, enormQ[k0]), __fmul_rn(2.0f, d0));
      float dq1 = __fsub_rn(__fadd_rn(Sx, enormQ[k1]), __fmul_rn(2.0f, d1));
      if (dq0 < best) { best = dq0; bi = k0; }   // ascending k: strict < = first index
      if (dq1 < best) { best = dq1; bi = k1; }
    }
    // lexicographic (value, index) wave reduction
    for (int off = 32; off > 0; off >>= 1) {
      float ob = __shfl_down(best, off);
      int oi = __shfl_down(bi, off);
      if (ob < best || (ob == best && oi < bi)) { best = ob; bi = oi; }
    }
    if (lane == 0) {
      selIdx[pix] = bi;
      out[OUT_IDX + pix] = (float)bi;
    }
  }
}

// ---------------- k_gather: gather + straight-through + loss ----------------
__global__ void k_gather(const float* __restrict__ lat, const float* __restrict__ emb,
                         const int* __restrict__ selIdx,
                         float* __restrict__ out, double* __restrict__ lossAcc) {
  __shared__ int sIdx[64];
  const int t = threadIdx.x;
  const int pix0 = blockIdx.x * 64;
  const int b = pix0 >> 10;
  const int hw0 = pix0 & 1023;
  const float* latBase = lat + (size_t)b * BSTRIDE + hw0;

  if (t < 64) sIdx[t] = selIdx[pix0 + t];
  __syncthreads();

  const int cSub = t >> 4;
  const int p4 = (t & 15) * 4;
  const int k0 = sIdx[p4], k1 = sIdx[p4+1], k2 = sIdx[p4+2], k3 = sIdx[p4+3];
  double lsum = 0.0;
  #pragma unroll 4
  for (int i = 0; i < 16; ++i) {
    int c = i * 16 + cSub;
    float4 l = *(const float4*)(latBase + (size_t)c * 1024 + p4);
    float q0 = emb[k0 * DIM + c], q1 = emb[k1 * DIM + c],
          q2 = emb[k2 * DIM + c], q3 = emb[k3 * DIM + c];
    float d0 = q0 - l.x, d1 = q1 - l.y, d2 = q2 - l.z, d3 = q3 - l.w;
    float4 o; o.x = l.x + d0; o.y = l.y + d1; o.z = l.z + d2; o.w = l.w + d3;
    *(float4*)(out + (size_t)b * BSTRIDE + (size_t)c * 1024 + hw0 + p4) = o;
    lsum += (double)d0*d0 + (double)d1*d1 + (double)d2*d2 + (double)d3*d3;
  }
  for (int off = 32; off > 0; off >>= 1) lsum += __shfl_down(lsum, off);
  if ((t & 63) == 0) atomicAdd(lossAcc, lsum);
}

__global__ void k_loss(const double* __restrict__ lossAcc, float* __restrict__ out) {
  double m = *lossAcc * (1.0 / 16777216.0);
  out[OUT_LOSS] = (float)(1.25 * m);
}

extern "C" void kernel_launch(void* const* d_in, const int* in_sizes, int n_in,
                              void* d_out, int out_size, void* d_ws, size_t ws_size,
                              hipStream_t stream) {
  const float* lat = (const float*)d_in[0];
  const float* emb = (const float*)d_in[1];
  float* out = (float*)d_out;
  char* ws = (char*)d_ws;
  double* lossAcc = (double*)(ws + WS_LOSS);
  int* count = (int*)(ws + WS_COUNT);
  float* enormQ = (float*)(ws + WS_ENORM);
  int* selIdx = (int*)(ws + WS_SEL);
  int* worklist = (int*)(ws + WS_WL);

  k_prep<<<dim3(16), dim3(64), 0, stream>>>(emb, enormQ, lossAcc, count);
  k_score<<<dim3(1024), dim3(256), 0, stream>>>(lat, emb, enormQ, selIdx, out, count, worklist);
  k_refine<<<dim3(512), dim3(256), 0, stream>>>(lat, emb, enormQ, count, worklist, selIdx, out);
  k_gather<<<dim3(1024), dim3(256), 0, stream>>>(lat, emb, selIdx, out, lossAcc);
  k_loss<<<dim3(1), dim3(1), 0, stream>>>(lossAcc, out);
}

// Round 3
// 655.325 us; speedup vs baseline: 1.7105x; 1.7105x over previous
//
#include <hip/hip_runtime.h>
#include <math.h>

// VectorQuantizer on MI355X.
// latents [64,256,32,32] f32, embedding [1024,256] f32.
// Outputs (concat fp32): quant_st [16777216], loss [1], indices-as-float [65536].
//
// Index semantics (VALIDATED bit-exact in round 2, absmax 0):
//   dist = fl32( fl32(Sx + Ek) - fl32(2*dot) ), argmin first-index ties,
// Sx/Ek = numpy pairwise fp32 (two 128-blocks, 8 accumulators each),
// dot = sequential ascending-c fp32 FMA chain (BLAS sgemm microkernel order).
// k_score's acc chain IS that exact chain, so the quantized argmin is computed
// directly in the scoring epilogue — no refine pass needed.
//
// Pipeline:
//  k_prep  : Ek[k] = numpy-pairwise fp32 sum(e_k^2); zero loss accumulator
//  k_score : tiled fp32 GEMM; fused numpy-pairwise Sx; exact quantized argmin
//  k_gather: gather + straight-through write + fp64 loss partials
//  k_loss  : loss = 1.25 * total / 16777216

#define DIM 256
#define BSTRIDE 262144      // 256*1024 elements per batch image
#define OUT_LOSS 16777216
#define OUT_IDX  16777217

// ws byte offsets
#define WS_LOSS  0
#define WS_ENORM 64
#define WS_SEL   8192

// ---------------- k_prep: numpy-pairwise |e_k|^2, zero loss ----------------
__global__ void k_prep(const float* __restrict__ emb, float* __restrict__ enormQ,
                       double* __restrict__ lossAcc) {
  const int k = blockIdx.x * 64 + threadIdx.x;   // 16 blocks x 64
  if (blockIdx.x == 0 && threadIdx.x == 0) *lossAcc = 0.0;
  if (k >= 1024) return;
  const float* e = emb + (size_t)k * DIM;
  float blk[2];
  #pragma unroll
  for (int h = 0; h < 2; ++h) {
    const float* a = e + h * 128;
    float r[8];
    #pragma unroll
    for (int j = 0; j < 8; ++j) r[j] = __fmul_rn(a[j], a[j]);
    for (int i = 8; i < 128; i += 8)
      #pragma unroll
      for (int j = 0; j < 8; ++j) r[j] = __fadd_rn(r[j], __fmul_rn(a[i+j], a[i+j]));
    blk[h] = __fadd_rn(__fadd_rn(__fadd_rn(r[0], r[1]), __fadd_rn(r[2], r[3])),
                       __fadd_rn(__fadd_rn(r[4], r[5]), __fadd_rn(r[6], r[7])));
  }
  enormQ[k] = __fadd_rn(blk[0], blk[1]);
}

// ---------------- k_score: fp32 tiled scoring, exact quantized argmin -------
// 1024 blocks x 256 threads; block = 64 pixels. Thread micro-tile 8x8.
__launch_bounds__(256, 2)
__global__ void k_score(const float* __restrict__ lat, const float* __restrict__ emb,
                        const float* __restrict__ enormQ,
                        int* __restrict__ selIdx, float* __restrict__ out) {
  __shared__ __align__(16) float smem[128*64 + 16*256 + 64];  // 49.3 KB
  float* latA = smem;            // [128][64]  c-major, pixels contiguous
  float* embB = smem + 128*64;   // [16][256]  c-major, embeddings contiguous
  float* sSx  = smem + 128*64 + 16*256;  // [64] per-pixel numpy-pairwise |x|^2

  const int t = threadIdx.x;
  const int pix0 = blockIdx.x * 64;
  const int b = pix0 >> 10;
  const int hw0 = pix0 & 1023;
  const float* latBase = lat + (size_t)b * BSTRIDE + hw0;

  const int tm = t & 7;          // pixel group: pixels tm*8..tm*8+7
  const int tn = t >> 3;         // emb group within chunk: tn*8..tn*8+7

  float bestV[8];
  int bestI[8];
  #pragma unroll
  for (int p = 0; p < 8; ++p) { bestV[p] = INFINITY; bestI[p] = 0; }
  float sxp[8];                  // per-pixel Sx cached in regs after chunk 0
  float sxPart = 0.0f;           // wave-0 half-0 pairwise partial

  const int cSub = t >> 4;
  const int p4   = (t & 15) * 4;
  const int eq   = t & 3;
  const int erb  = (t >> 2) * 4;

  for (int chunk = 0; chunk < 4; ++chunk) {
    const int kBase = chunk * 256;
    float acc[8][8];
    #pragma unroll
    for (int p = 0; p < 8; ++p)
      #pragma unroll
      for (int j = 0; j < 8; ++j) acc[p][j] = 0.0f;

    for (int half = 0; half < 2; ++half) {
      const int cHalf = half * 128;
      __syncthreads();
      // stage latA[128][64]
      #pragma unroll
      for (int i = 0; i < 8; ++i) {
        int c = i * 16 + cSub;
        float4 v = *(const float4*)(latBase + (size_t)(cHalf + c) * 1024 + p4);
        *(float4*)(latA + c * 64 + p4) = v;
      }
      for (int stageI = 0; stageI < 8; ++stageI) {
        const int c0 = stageI * 16;
        __syncthreads();
        // stage embB[16][256] (transpose-at-store)
        #pragma unroll
        for (int i = 0; i < 4; ++i) {
          int n = erb + i;
          float4 v = *(const float4*)(emb + (size_t)(kBase + n) * DIM + cHalf + c0 + eq * 4);
          embB[(eq*4 + 0) * 256 + n] = v.x;
          embB[(eq*4 + 1) * 256 + n] = v.y;
          embB[(eq*4 + 2) * 256 + n] = v.z;
          embB[(eq*4 + 3) * 256 + n] = v.w;
        }
        __syncthreads();
        // fused Sx: wave 0 computes the numpy-pairwise 128-block partial for
        // pixel t from the freshly staged latA (stable for this whole half)
        if (chunk == 0 && stageI == 0 && t < 64) {
          float r[8];
          #pragma unroll
          for (int j = 0; j < 8; ++j) { float x = latA[j * 64 + t]; r[j] = __fmul_rn(x, x); }
          for (int i = 8; i < 128; i += 8)
            #pragma unroll
            for (int j = 0; j < 8; ++j) { float x = latA[(i + j) * 64 + t]; r[j] = __fadd_rn(r[j], __fmul_rn(x, x)); }
          float blk = __fadd_rn(__fadd_rn(__fadd_rn(r[0], r[1]), __fadd_rn(r[2], r[3])),
                                __fadd_rn(__fadd_rn(r[4], r[5]), __fadd_rn(r[6], r[7])));
          if (half == 0) sxPart = blk;
          else sSx[t] = __fadd_rn(sxPart, blk);   // visible after next barrier
        }
        #pragma unroll
        for (int kc = 0; kc < 16; ++kc) {
          float4 l0 = *(const float4*)(latA + (c0 + kc) * 64 + tm * 8);
          float4 l1 = *(const float4*)(latA + (c0 + kc) * 64 + tm * 8 + 4);
          float4 e0 = *(const float4*)(embB + kc * 256 + tn * 8);
          float4 e1 = *(const float4*)(embB + kc * 256 + tn * 8 + 4);
          float lv[8] = {l0.x,l0.y,l0.z,l0.w,l1.x,l1.y,l1.z,l1.w};
          float ev[8] = {e0.x,e0.y,e0.z,e0.w,e1.x,e1.y,e1.z,e1.w};
          #pragma unroll
          for (int p = 0; p < 8; ++p)
            #pragma unroll
            for (int j = 0; j < 8; ++j)
              acc[p][j] = fmaf(lv[p], ev[j], acc[p][j]);   // ascending-c chain
        }
      }
    }
    // chunk epilogue: exact quantized score, first-index streaming argmin
    // (per-thread candidate k's ascend: strict < keeps earliest index)
    if (chunk == 0) {
      #pragma unroll
      for (int p = 0; p < 8; ++p) sxp[p] = sSx[tm * 8 + p];  // ready since stageI 1
    }
    #pragma unroll
    for (int j = 0; j < 8; ++j) {
      const int kIdx = kBase + tn * 8 + j;
      const float en = enormQ[kIdx];
      #pragma unroll
      for (int p = 0; p < 8; ++p) {
        float dq = __fsub_rn(__fadd_rn(sxp[p], en), __fmul_rn(2.0f, acc[p][j]));
        if (dq < bestV[p]) { bestV[p] = dq; bestI[p] = kIdx; }
      }
    }
  }

  // merge top-1 across the 32 tn-threads per pixel
  __syncthreads();
  float2* mb = (float2*)smem;   // [64][33] float2 = 33 KB region, no sSx overlap
  #pragma unroll
  for (int p = 0; p < 8; ++p) {
    float2 v;
    v.x = bestV[p]; v.y = __int_as_float(bestI[p]);
    mb[(tm * 8 + p) * 33 + tn] = v;
  }
  __syncthreads();
  if (t < 64) {
    float B1 = INFINITY;
    int I1 = 0;
    for (int j = 0; j < 32; ++j) {
      float2 v = mb[t * 33 + j];
      float c1 = v.x;
      int ci1 = __float_as_int(v.y);
      if (c1 < B1 || (c1 == B1 && ci1 < I1)) { B1 = c1; I1 = ci1; }
    }
    const int pix = pix0 + t;
    selIdx[pix] = I1;
    out[OUT_IDX + pix] = (float)I1;
  }
}

// ---------------- k_gather: gather + straight-through + loss ----------------
__global__ void k_gather(const float* __restrict__ lat, const float* __restrict__ emb,
                         const int* __restrict__ selIdx,
                         float* __restrict__ out, double* __restrict__ lossAcc) {
  __shared__ int sIdx[64];
  const int t = threadIdx.x;
  const int pix0 = blockIdx.x * 64;
  const int b = pix0 >> 10;
  const int hw0 = pix0 & 1023;
  const float* latBase = lat + (size_t)b * BSTRIDE + hw0;

  if (t < 64) sIdx[t] = selIdx[pix0 + t];
  __syncthreads();

  const int cSub = t >> 4;
  const int p4 = (t & 15) * 4;
  const int k0 = sIdx[p4], k1 = sIdx[p4+1], k2 = sIdx[p4+2], k3 = sIdx[p4+3];
  double lsum = 0.0;
  #pragma unroll 4
  for (int i = 0; i < 16; ++i) {
    int c = i * 16 + cSub;
    float4 l = *(const float4*)(latBase + (size_t)c * 1024 + p4);
    float q0 = emb[k0 * DIM + c], q1 = emb[k1 * DIM + c],
          q2 = emb[k2 * DIM + c], q3 = emb[k3 * DIM + c];
    float d0 = q0 - l.x, d1 = q1 - l.y, d2 = q2 - l.z, d3 = q3 - l.w;
    float4 o; o.x = l.x + d0; o.y = l.y + d1; o.z = l.z + d2; o.w = l.w + d3;
    *(float4*)(out + (size_t)b * BSTRIDE + (size_t)c * 1024 + hw0 + p4) = o;
    lsum += (double)d0*d0 + (double)d1*d1 + (double)d2*d2 + (double)d3*d3;
  }
  for (int off = 32; off > 0; off >>= 1) lsum += __shfl_down(lsum, off);
  if ((t & 63) == 0) atomicAdd(lossAcc, lsum);
}

__global__ void k_loss(const double* __restrict__ lossAcc, float* __restrict__ out) {
  double m = *lossAcc * (1.0 / 16777216.0);
  out[OUT_LOSS] = (float)(1.25 * m);
}

extern "C" void kernel_launch(void* const* d_in, const int* in_sizes, int n_in,
                              void* d_out, int out_size, void* d_ws, size_t ws_size,
                              hipStream_t stream) {
  const float* lat = (const float*)d_in[0];
  const float* emb = (const float*)d_in[1];
  float* out = (float*)d_out;
  char* ws = (char*)d_ws;
  double* lossAcc = (double*)(ws + WS_LOSS);
  float* enormQ = (float*)(ws + WS_ENORM);
  int* selIdx = (int*)(ws + WS_SEL);

  k_prep<<<dim3(16), dim3(64), 0, stream>>>(emb, enormQ, lossAcc);
  k_score<<<dim3(1024), dim3(256), 0, stream>>>(lat, emb, enormQ, selIdx, out);
  k_gather<<<dim3(1024), dim3(256), 0, stream>>>(lat, emb, selIdx, out, lossAcc);
  k_loss<<<dim3(1), dim3(1), 0, stream>>>(lossAcc, out);
}